// Round 20
// baseline (224.968 us; speedup 1.0000x reference)
//
#include <hip/hip_runtime.h>
#include <hip/hip_bf16.h>

typedef __bf16 bf16_t;
typedef __bf16 bf16x2 __attribute__((ext_vector_type(2)));
typedef __bf16 bf16x4v __attribute__((ext_vector_type(4)));
typedef __bf16 bf16x8 __attribute__((ext_vector_type(8)));
typedef float f32x4 __attribute__((ext_vector_type(4)));

#define LOG2E 1.4426950408889634f
// (1/sqrt(128)) * log2(e), folded into Q at ln_rope time
#define QSCALE (0.08838834764831843f * 1.4426950408889634f)

// ------- fused fp32->bf16 conversion (x, w_qkv, w_o) + RoPE tables, one launch ----
__global__ __launch_bounds__(256) void cvt_all(const float* __restrict__ x, bf16_t* __restrict__ xb,
                                               const float* __restrict__ wq, bf16_t* __restrict__ wqb,
                                               const float* __restrict__ wo, bf16_t* __restrict__ wob,
                                               float* __restrict__ cosT, float* __restrict__ sinT) {
  int i = blockIdx.x * 256 + threadIdx.x;
  if (i < 5767168) {                     // float4 conversions
    const float* in; bf16_t* out; int idx;
    if (i < 2097152)      { in = x;  out = xb;  idx = i; }
    else if (i < 4718592) { in = wq; out = wqb; idx = i - 2097152; }
    else                  { in = wo; out = wob; idx = i - 4718592; }
    float4 v = ((const float4*)in)[idx];
    bf16x4v o;
    o[0] = (__bf16)v.x; o[1] = (__bf16)v.y; o[2] = (__bf16)v.z; o[3] = (__bf16)v.w;
    *(bf16x4v*)(out + (size_t)idx * 4) = o;
  } else {                               // rope tables: 2048*64 entries
    int idx = i - 5767168;
    int s = idx >> 6, fi = idx & 63;
    float inv = __builtin_amdgcn_exp2f(-(float)fi * (19.931568569324174f / 64.0f));
    float f = (float)s * inv;
    cosT[idx] = cosf(f);
    sinT[idx] = sinf(f);
  }
}

// ------- GEMM1: single-buffered <4,NI>, 2 blocks/CU anti-phase overlap (R19) ----
template<int NI, typename OT>
__global__ __launch_bounds__(512, 4) void gemm4s(const bf16_t* __restrict__ A,
                                                 const bf16_t* __restrict__ B,
                                                 OT* __restrict__ C,
                                                 int M, int N, int K) {
  constexpr int BM = 128;
  constexpr int BN = NI * 64;
  constexpr int NA = 2;
  constexpr int NB = NI;
  constexpr int ST = NA + NB;

  __shared__ bf16_t LA[BM * 64];
  __shared__ bf16_t LB[BN * 64];

  int nb = N / BN;
  int cpx = gridDim.x >> 3;              // grid divisible by 8
  int bid = blockIdx.x;
  int swz = (bid & 7) * cpx + (bid >> 3);
  int bm = swz / nb, bn = swz % nb;
  int m0 = bm * BM, n0 = bn * BN;
  int tid = threadIdx.x, lane = tid & 63, wv = tid >> 6;
  int wr = wv >> 2, wc = wv & 3, lr = lane & 15, g = lane >> 4;
  int T = K >> 6;

  auto stageI = [&](int kt, int s) {
    int k0 = kt << 6;
    if (s < NA) {
      int c = s * 512 + tid;
      int row = c >> 3, lc = (c & 7) ^ (row & 7);
      __builtin_amdgcn_global_load_lds(
          (const __attribute__((address_space(1))) void*)(A + (size_t)(m0 + row) * K + k0 + lc * 8),
          (__attribute__((address_space(3))) void*)&LA[(s * 512 + wv * 64) * 8], 16, 0, 0);
    } else {
      int c = (s - NA) * 512 + tid;
      int row = c >> 3, lc = (c & 7) ^ (row & 7);
      __builtin_amdgcn_global_load_lds(
          (const __attribute__((address_space(1))) void*)(B + (size_t)(n0 + row) * K + k0 + lc * 8),
          (__attribute__((address_space(3))) void*)&LB[((s - NA) * 512 + wv * 64) * 8], 16, 0, 0);
    }
  };

  f32x4 acc[4][NI];
#pragma unroll
  for (int i = 0; i < 4; i++)
#pragma unroll
    for (int j = 0; j < NI; j++)
#pragma unroll
      for (int r = 0; r < 4; r++) acc[i][j][r] = 0.f;

  int ofk0 = ((0 + g) ^ (lr & 7)) << 3;
  int ofk1 = ((4 + g) ^ (lr & 7)) << 3;
  int offA = (wr * 64 + lr) * 64;
  int offB = (wc * (NI * 16) + lr) * 64;

  for (int t = 0; t < T; t++) {
#pragma unroll
    for (int s = 0; s < ST; s++) stageI(t, s);
    asm volatile("s_waitcnt vmcnt(0)" ::: "memory");
    __builtin_amdgcn_s_barrier();
    asm volatile("" ::: "memory");

#pragma unroll
    for (int ks = 0; ks < 2; ks++) {
      const int ofk = ks ? ofk1 : ofk0;
      bf16x8 bq[NI];
#pragma unroll
      for (int ni = 0; ni < NI; ni++) bq[ni] = *(const bf16x8*)&LB[offB + ni * 1024 + ofk];
#pragma unroll
      for (int i = 0; i < 4; i++) {
        bf16x8 af = *(const bf16x8*)&LA[offA + i * 1024 + ofk];
#pragma unroll
        for (int ni = 0; ni < NI; ni++)
          acc[i][ni] = __builtin_amdgcn_mfma_f32_16x16x32_bf16(af, bq[ni], acc[i][ni], 0, 0, 0);
      }
    }

    if (t + 1 < T) {
      asm volatile("s_waitcnt lgkmcnt(0)" ::: "memory");
      __builtin_amdgcn_s_barrier();
      asm volatile("" ::: "memory");
    }
  }

#pragma unroll
  for (int mi = 0; mi < 4; mi++)
#pragma unroll
    for (int ni = 0; ni < NI; ni++) {
      int m = m0 + wr * 64 + mi * 16 + g * 4;
      int n = n0 + wc * (NI * 16) + ni * 16 + lr;
#pragma unroll
      for (int r = 0; r < 4; r++) C[(size_t)(m + r) * N + n] = (OT)acc[mi][ni][r];
    }
}

// ---------------- bf16 NT GEMM: free-flow compute, ONE barrier per K-tile -------
// (R13/R14-proven structure; used for GEMM2.)
template<int MI, int NI, typename OT>
__global__ __launch_bounds__(512) void gemm8p(const bf16_t* __restrict__ A,
                                              const bf16_t* __restrict__ B,
                                              OT* __restrict__ C,
                                              int M, int N, int K) {
  constexpr int BM = MI * 32;
  constexpr int BN = NI * 64;
  constexpr int NA = BM / 64;
  constexpr int NB = BN / 64;
  constexpr int ST = NA + NB;

  __shared__ bf16_t LA[2][BM * 64];
  __shared__ bf16_t LB[2][BN * 64];

  int nb = N / BN;
  int cpx = gridDim.x >> 3;
  int bid = blockIdx.x;
  int swz = (bid & 7) * cpx + (bid >> 3);
  int bm = swz / nb, bn = swz % nb;
  int m0 = bm * BM, n0 = bn * BN;
  int tid = threadIdx.x, lane = tid & 63, wv = tid >> 6;
  int wr = wv >> 2, wc = wv & 3, lr = lane & 15, g = lane >> 4;
  int T = K >> 6;

  auto stageI = [&](int kt, int bi, int s) {
    int k0 = kt << 6;
    if (s < NA) {
      int c = s * 512 + tid;
      int row = c >> 3, lc = (c & 7) ^ (row & 7);
      __builtin_amdgcn_global_load_lds(
          (const __attribute__((address_space(1))) void*)(A + (size_t)(m0 + row) * K + k0 + lc * 8),
          (__attribute__((address_space(3))) void*)&LA[bi][(s * 512 + wv * 64) * 8], 16, 0, 0);
    } else {
      int c = (s - NA) * 512 + tid;
      int row = c >> 3, lc = (c & 7) ^ (row & 7);
      __builtin_amdgcn_global_load_lds(
          (const __attribute__((address_space(1))) void*)(B + (size_t)(n0 + row) * K + k0 + lc * 8),
          (__attribute__((address_space(3))) void*)&LB[bi][((s - NA) * 512 + wv * 64) * 8], 16, 0, 0);
    }
  };

  f32x4 acc[MI][NI];
#pragma unroll
  for (int i = 0; i < MI; i++)
#pragma unroll
    for (int j = 0; j < NI; j++)
#pragma unroll
      for (int r = 0; r < 4; r++) acc[i][j][r] = 0.f;

#pragma unroll
  for (int s = 0; s < ST; s++) stageI(0, 0, s);
  asm volatile("s_waitcnt vmcnt(0)" ::: "memory");
  __builtin_amdgcn_s_barrier();
  asm volatile("" ::: "memory");

  int ofk0 = ((0 + g) ^ (lr & 7)) << 3;
  int ofk1 = ((4 + g) ^ (lr & 7)) << 3;
  int offA = (wr * (MI * 16) + lr) * 64;
  int offB = (wc * (NI * 16) + lr) * 64;

  for (int t = 0; t < T; t++) {
    int bi = t & 1, bo = bi ^ 1;
    const bf16_t* la = LA[bi];
    const bf16_t* lb = LB[bi];
    bool pre = (t + 1 < T);
    if (pre) {
#pragma unroll
      for (int s = 0; s < ST; s++) stageI(t + 1, bo, s);
    }

    bf16x8 bq0[NI], bq1[NI];
#pragma unroll
    for (int ni = 0; ni < NI; ni++) bq0[ni] = *(const bf16x8*)&lb[offB + ni * 1024 + ofk0];
#pragma unroll
    for (int ni = 0; ni < NI; ni++) bq1[ni] = *(const bf16x8*)&lb[offB + ni * 1024 + ofk1];
#pragma unroll
    for (int q = 0; q < MI / 4; q++) {
      bf16x8 af0[4], af1[4];
#pragma unroll
      for (int i = 0; i < 4; i++)
        af0[i] = *(const bf16x8*)&la[offA + (q * 4 + i) * 1024 + ofk0];
#pragma unroll
      for (int i = 0; i < 4; i++)
#pragma unroll
        for (int ni = 0; ni < NI; ni++)
          acc[q * 4 + i][ni] =
              __builtin_amdgcn_mfma_f32_16x16x32_bf16(af0[i], bq0[ni], acc[q * 4 + i][ni], 0, 0, 0);
#pragma unroll
      for (int i = 0; i < 4; i++)
        af1[i] = *(const bf16x8*)&la[offA + (q * 4 + i) * 1024 + ofk1];
#pragma unroll
      for (int i = 0; i < 4; i++)
#pragma unroll
        for (int ni = 0; ni < NI; ni++)
          acc[q * 4 + i][ni] =
              __builtin_amdgcn_mfma_f32_16x16x32_bf16(af1[i], bq1[ni], acc[q * 4 + i][ni], 0, 0, 0);
    }

    if (pre) {
      asm volatile("s_waitcnt vmcnt(0) lgkmcnt(0)" ::: "memory");
      __builtin_amdgcn_s_barrier();
      asm volatile("" ::: "memory");
    }
  }

#pragma unroll
  for (int mi = 0; mi < MI; mi++)
#pragma unroll
    for (int ni = 0; ni < NI; ni++) {
      int m = m0 + wr * (MI * 16) + mi * 16 + g * 4;
      int n = n0 + wc * (NI * 16) + ni * 16 + lr;
#pragma unroll
      for (int r = 0; r < 4; r++) C[(size_t)(m + r) * N + n] = (OT)acc[mi][ni][r];
    }
}

// ---------------- fused per-head LayerNorm + RoPE -> bf16 Q(B,H,S,D), K(B,KV,S,D) ----
__global__ __launch_bounds__(256) void ln_rope(const bf16_t* __restrict__ qkv,
                                               const float* __restrict__ qw, const float* __restrict__ qb,
                                               const float* __restrict__ kw, const float* __restrict__ kb,
                                               const float* __restrict__ cosT, const float* __restrict__ sinT,
                                               bf16_t* __restrict__ Qr, bf16_t* __restrict__ Kr) {
  int row = blockIdx.x;              // b*2048 + s
  int b = row >> 11, s = row & 2047;
  int tid = threadIdx.x, gi = tid >> 4, li = tid & 15;
  const bf16_t* base = qkv + (size_t)row * 5120;
  float4 c4 = *(const float4*)(cosT + (s << 6) + (li << 2));
  float4 s4 = *(const float4*)(sinT + (s << 6) + (li << 2));
#pragma unroll
  for (int it = 0; it < 2; it++) {
    int head;
    if (it == 0) head = gi;            // 16 q heads across 16 groups
    else { if (gi >= 4) break; head = 16 + gi; }   // 4 k heads on wave 0
    bool isq = (it == 0);
    int off = isq ? (head << 7) : (4096 + ((head - 16) << 7));
    bf16x8 xv = *(const bf16x8*)(base + off + (li << 3));
    float xf[8];
#pragma unroll
    for (int j = 0; j < 8; j++) xf[j] = (float)xv[j];
    float sum = 0.f;
#pragma unroll
    for (int j = 0; j < 8; j++) sum += xf[j];
#pragma unroll
    for (int m = 1; m < 16; m <<= 1) sum += __shfl_xor(sum, m);
    float mu = sum * 0.0078125f;
    float vs = 0.f;
#pragma unroll
    for (int j = 0; j < 8; j++) { xf[j] -= mu; vs += xf[j] * xf[j]; }
#pragma unroll
    for (int m = 1; m < 16; m <<= 1) vs += __shfl_xor(vs, m);
    float rs = rsqrtf(vs * 0.0078125f + 1e-6f);
    const float* w = isq ? qw : kw;
    const float* bb = isq ? qb : kb;
    float4 w0 = *(const float4*)(w + (li << 3));
    float4 w1 = *(const float4*)(w + (li << 3) + 4);
    float4 b0 = *(const float4*)(bb + (li << 3));
    float4 b1 = *(const float4*)(bb + (li << 3) + 4);
    float y[8];
    y[0] = xf[0] * rs * w0.x + b0.x; y[1] = xf[1] * rs * w0.y + b0.y;
    y[2] = xf[2] * rs * w0.z + b0.z; y[3] = xf[3] * rs * w0.w + b0.w;
    y[4] = xf[4] * rs * w1.x + b1.x; y[5] = xf[5] * rs * w1.y + b1.y;
    y[6] = xf[6] * rs * w1.z + b1.z; y[7] = xf[7] * rs * w1.w + b1.w;
    float cc[4] = { c4.x, c4.y, c4.z, c4.w };
    float ss[4] = { s4.x, s4.y, s4.z, s4.w };
    bf16x8 ov;
#pragma unroll
    for (int p = 0; p < 4; p++) {
      float o0 = y[2 * p] * cc[p] - y[2 * p + 1] * ss[p];
      float o1 = y[2 * p] * ss[p] + y[2 * p + 1] * cc[p];
      if (isq) { o0 *= QSCALE; o1 *= QSCALE; }
      ov[2 * p] = (__bf16)o0; ov[2 * p + 1] = (__bf16)o1;
    }
    size_t dst = isq ? ((((size_t)(b * 16 + head)) * 2048 + s) * 128 + (li << 3))
                     : ((((size_t)(b * 4 + (head - 16))) * 2048 + s) * 128 + (li << 3));
    *(bf16x8*)((isq ? Qr : Kr) + dst) = ov;
  }
}

// ---------------- V transpose: qkv v-slice (B,S,KV,D) -> Vt (B,KV,D,S) bf16 -------
__global__ __launch_bounds__(256) void vtrans(const bf16_t* __restrict__ qkv,
                                              bf16_t* __restrict__ Vt) {
  int bid = blockIdx.x;              // ((b*4+kv)*64 + sb)
  int sb = bid & 63, kv = (bid >> 6) & 3, b = bid >> 8;
  int s0 = sb << 5;
  __shared__ bf16_t T[128 * 33];
  int tid = threadIdx.x;
#pragma unroll
  for (int i = 0; i < 16; i++) {
    int idx = i * 256 + tid;         // 0..4095
    int r = idx >> 7, d = idx & 127;
    T[d * 33 + r] = qkv[((size_t)(b * 2048 + s0 + r)) * 5120 + 4608 + (kv << 7) + d];
  }
  __syncthreads();
#pragma unroll
  for (int j = 0; j < 16; j++) {
    int idx = j * 256 + tid;
    int d = idx >> 5, sc = idx & 31;
    Vt[(((size_t)(b * 4 + kv)) * 128 + d) * 2048 + s0 + sc] = T[d * 33 + sc];
  }
}

// ---------------- causal GQA flash attention + sigmoid gate -> ag bf16 (B,S,H*D) ----
// R10/R14 structure. NEW (this round): K swizzle key s2(row) = (row&3)|((row>>3&1)<<2)
// replaces (row&15). pi(lr) rows have bit2==0, so the old XOR key spanned only 4 of
// 8 bank groups (16 lanes per 4-bank group = 2x read time, the measured 4.26M
// conflict cycles). s2 recovers a varying bit2 from row bit3 -> uniform 8-group
// spread -> ds_read_b128 at the conflict-free minimum. Applied BOTH sides.
__global__ __launch_bounds__(256, 3) void attn(const bf16_t* __restrict__ Qr,
                                               const bf16_t* __restrict__ Kr,
                                               const bf16_t* __restrict__ Vt,
                                               const bf16_t* __restrict__ qkv,
                                               bf16_t* __restrict__ ag) {
  __shared__ bf16_t Ks[2][32 * 128];   // 16 KB: K tiles, XOR s2(row)
  __shared__ bf16_t Vs[2][128 * 32];   // 16 KB: V^T tiles, XOR (d>>1)&3
  int bid = blockIdx.x;                // 512 = 16 pr * (16 h * 2 b)
  int hb = bid & 31;
  int h = hb & 15, b = hb >> 4;
  int pr = bid >> 5;                   // 0..15
  int kvh = h >> 2;
  int tid = threadIdx.x, lane = tid & 63, wv = tid >> 6;
  int lr = lane & 15, g = lane >> 4;
  int r0base = ((lr >> 2) << 3) + (lr & 3);   // pi(lr): A-row -> K-row map

  const bf16_t* Kg = Kr + ((size_t)(b * 4 + kvh)) * 2048 * 128;
  const bf16_t* Vg = Vt + ((size_t)(b * 4 + kvh)) * 128 * 2048;

  auto s2 = [](int row) { return (row & 3) | (((row >> 3) & 1) << 2); };

  auto stage = [&](int buf, int kv0) {
#pragma unroll
    for (int i = 0; i < 2; i++) {      // K: 8 KB, 512 chunks of 16 B
      int c = i * 256 + tid;
      int row = c >> 4, lc = (c & 15) ^ ((row & 3) | (((row >> 3) & 1) << 2));
      __builtin_amdgcn_global_load_lds(
          (const __attribute__((address_space(1))) void*)(Kg + (size_t)(kv0 + row) * 128 + lc * 8),
          (__attribute__((address_space(3))) void*)&Ks[buf][c * 8], 16, 0, 0);
    }
#pragma unroll
    for (int i = 0; i < 2; i++) {      // V: 8 KB
      int c = i * 256 + tid;
      int d = c >> 2, cv = (c & 3) ^ ((d >> 1) & 3);
      __builtin_amdgcn_global_load_lds(
          (const __attribute__((address_space(1))) void*)(Vg + (size_t)d * 2048 + kv0 + cv * 8),
          (__attribute__((address_space(3))) void*)&Vs[buf][c * 8], 16, 0, 0);
    }
  };

  auto sm = [&](const f32x4& s0, const f32x4& s1, int qrow, int kvabs, bool dia,
                float& mrun, float& lsp, bf16x8& pb, f32x4 (&oac)[8]) {
    float tt[8];
#pragma unroll
    for (int r = 0; r < 4; r++) { tt[r] = s0[r]; tt[4 + r] = s1[r]; }
    if (dia) {
#pragma unroll
      for (int r = 0; r < 4; r++) {
        if (kvabs + r > qrow)     tt[r]     = -1e30f;
        if (kvabs + 4 + r > qrow) tt[4 + r] = -1e30f;
      }
    }
    float lm = fmaxf(fmaxf(fmaxf(tt[0], tt[1]), tt[2]),
                     fmaxf(fmaxf(tt[3], tt[4]), fmaxf(fmaxf(tt[5], tt[6]), tt[7])));
    if (__all(lm <= mrun + 8.f)) {      // defer-max common path: lane-local only
      float ps = 0.f;
#pragma unroll
      for (int i = 0; i < 8; i++) {
        float pv = __builtin_amdgcn_exp2f(tt[i] - mrun);
        pb[i] = (__bf16)pv; ps += pv;
      }
      lsp += ps;
    } else {                            // rare rescale path
      float pm = lm;
      pm = fmaxf(pm, __shfl_xor(pm, 16));
      pm = fmaxf(pm, __shfl_xor(pm, 32));
      float mnew = fmaxf(mrun, pm);
      float corr = __builtin_amdgcn_exp2f(mrun - mnew);
      float ps = 0.f;
#pragma unroll
      for (int i = 0; i < 8; i++) {
        float pv = __builtin_amdgcn_exp2f(tt[i] - mnew);
        pb[i] = (__bf16)pv; ps += pv;
      }
      lsp = lsp * corr + ps;
      mrun = mnew;
#pragma unroll
      for (int dt = 0; dt < 8; dt++)
#pragma unroll
        for (int r = 0; r < 4; r++) oac[dt][r] *= corr;
    }
  };

  for (int phase = 0; phase < 2; phase++) {
    int qb = phase ? (31 - pr) : pr;   // 64-row q-block index
    int qw0 = qb << 6;
    int qw = qw0 + (wv << 4);          // wave q base (16 rows)
    int qrow = qw + lr;
    int qmax = qw + 15;
    int nt = (qb + 1) << 1;            // 32-wide kv tiles

    const bf16_t* Qg = Qr + (((size_t)(b * 16 + h)) * 2048 + qrow) * 128;
    bf16x8 qf[4];
#pragma unroll
    for (int ds = 0; ds < 4; ds++) qf[ds] = *(const bf16x8*)(Qg + ds * 32 + g * 8);

    f32x4 oa[8];
#pragma unroll
    for (int i = 0; i < 8; i++)
#pragma unroll
      for (int r = 0; r < 4; r++) oa[i][r] = 0.f;
    float mrun = -1e30f, lsp = 0.f;

    stage(0, 0);
    asm volatile("s_waitcnt vmcnt(0)" ::: "memory");
    __builtin_amdgcn_s_barrier();
    asm volatile("" ::: "memory");
    for (int t = 0; t < nt; t++) {
      int cur = t & 1;
      if (t + 1 < nt) stage(cur ^ 1, (t + 1) << 5);
      int kvb = t << 5;
      if (kvb <= qmax) {
        const bf16_t* kb = Ks[cur];
        const bf16_t* vb = Vs[cur];
        int ra = r0base, rb2 = r0base + 4;
        int sa = s2(ra), sb2 = s2(rb2);
        bf16x8 a0[4], a1[4];
#pragma unroll
        for (int ds = 0; ds < 4; ds++) {
          a0[ds] = *(const bf16x8*)&kb[ra * 128 + (((ds * 4 + g) ^ sa) << 3)];
          a1[ds] = *(const bf16x8*)&kb[rb2 * 128 + (((ds * 4 + g) ^ sb2) << 3)];
        }
        f32x4 s0, s1;
#pragma unroll
        for (int r = 0; r < 4; r++) { s0[r] = 0.f; s1[r] = 0.f; }
        __builtin_amdgcn_s_setprio(1);
#pragma unroll
        for (int ds = 0; ds < 4; ds++) {
          s0 = __builtin_amdgcn_mfma_f32_16x16x32_bf16(a0[ds], qf[ds], s0, 0, 0, 0);
          s1 = __builtin_amdgcn_mfma_f32_16x16x32_bf16(a1[ds], qf[ds], s1, 0, 0, 0);
        }
        __builtin_amdgcn_s_setprio(0);
        int kvabs = kvb + (g << 3);
        bool dia = (kvb + 31 > qw);
        bf16x8 pb;
        sm(s0, s1, qrow, kvabs, dia, mrun, lsp, pb, oa);
        __builtin_amdgcn_s_setprio(1);
#pragma unroll
        for (int dt = 0; dt < 8; dt++) {
          int d = dt * 16 + lr;
          bf16x8 va = *(const bf16x8*)&vb[d * 32 + ((g ^ ((d >> 1) & 3)) << 3)];
          oa[dt] = __builtin_amdgcn_mfma_f32_16x16x32_bf16(va, pb, oa[dt], 0, 0, 0);
        }
        __builtin_amdgcn_s_setprio(0);
      }
      asm volatile("s_waitcnt vmcnt(0) lgkmcnt(0)" ::: "memory");
      __builtin_amdgcn_s_barrier();
      asm volatile("" ::: "memory");
    }

    float ls = lsp + __shfl_xor(lsp, 16);
    ls += __shfl_xor(ls, 32);
    float invl = __builtin_amdgcn_rcpf(ls);

    size_t ob = ((size_t)b * 2048 + qrow) * 2048 + (h << 7);
    size_t gb = ((size_t)b * 2048 + qrow) * 5120 + 2048 + (h << 7);
#pragma unroll
    for (int dt = 0; dt < 8; dt++) {
      int d = dt * 16 + (g << 2);
      bf16x4v gt = *(const bf16x4v*)(qkv + gb + d);
      bf16x4v o;
#pragma unroll
      for (int r = 0; r < 4; r++)
        o[r] = (__bf16)(oa[dt][r] * invl *
                        __builtin_amdgcn_rcpf(1.f + __builtin_amdgcn_exp2f(-(float)gt[r] * LOG2E)));
      *(bf16x4v*)(ag + ob + d) = o;
    }
  }
}

// ---------------- launch ----------------
extern "C" void kernel_launch(void* const* d_in, const int* in_sizes, int n_in,
                              void* d_out, int out_size, void* d_ws, size_t ws_size,
                              hipStream_t stream) {
  const float* x    = (const float*)d_in[0];
  const float* wqkv = (const float*)d_in[1];
  const float* wo   = (const float*)d_in[2];
  const float* qnw  = (const float*)d_in[3];
  const float* qnb  = (const float*)d_in[4];
  const float* knw  = (const float*)d_in[5];
  const float* knb  = (const float*)d_in[6];
  float* out = (float*)d_out;

  char* p = (char*)d_ws;
  bf16_t* xb  = (bf16_t*)p;           // 16 MB, reused as ag after GEMM1
  bf16_t* ag  = xb;
  p += (size_t)16777216;
  bf16_t* wqb = (bf16_t*)p;           // 20 MB, reused as Qr after GEMM1
  bf16_t* Qr  = wqb;
  p += (size_t)20971520;
  bf16_t* wob = (bf16_t*)p; p += (size_t)8388608;
  bf16_t* qkv = (bf16_t*)p; p += (size_t)41943040;   // bf16 qkv (B,S,5120)
  bf16_t* Kr  = (bf16_t*)p; p += (size_t)4194304;
  bf16_t* Vt  = (bf16_t*)p; p += (size_t)4194304;
  float* cosT = (float*)p;  p += (size_t)524288;
  float* sinT = (float*)p;  p += (size_t)524288;

  cvt_all<<<23040, 256, 0, stream>>>(x, xb, wqkv, wqb, wo, wob, cosT, sinT);

  // qkv = x @ w_qkv^T   (4096 x 5120 x K=2048): 512 blocks, single-buffer, 2/CU
  gemm4s<5, bf16_t><<<512, 512, 0, stream>>>(xb, wqb, qkv, 4096, 5120, 2048);

  ln_rope<<<4096, 256, 0, stream>>>(qkv, qnw, qnb, knw, knb, cosT, sinT, Qr, Kr);
  vtrans<<<512, 256, 0, stream>>>(qkv, Vt);

  attn<<<512, 256, 0, stream>>>(Qr, Kr, Vt, qkv, ag);

  // out = ag @ w_o^T    (4096 x 2048 x K=2048): BM=128, BN=256 -> 256 blocks, f32 out
  gemm8p<4, 4, float><<<256, 512, 0, stream>>>(ag, wob, out, 4096, 2048, 2048);
}

// Round 21
// 223.210 us; speedup vs baseline: 1.0079x; 1.0079x over previous
//
#include <hip/hip_runtime.h>
#include <hip/hip_bf16.h>

typedef __bf16 bf16_t;
typedef __bf16 bf16x2 __attribute__((ext_vector_type(2)));
typedef __bf16 bf16x4v __attribute__((ext_vector_type(4)));
typedef __bf16 bf16x8 __attribute__((ext_vector_type(8)));
typedef float f32x4 __attribute__((ext_vector_type(4)));

#define LOG2E 1.4426950408889634f
// (1/sqrt(128)) * log2(e), folded into Q at ln_rope time
#define QSCALE (0.08838834764831843f * 1.4426950408889634f)

// ------- fused fp32->bf16 conversion (x, w_qkv, w_o) + RoPE tables, one launch ----
__global__ __launch_bounds__(256) void cvt_all(const float* __restrict__ x, bf16_t* __restrict__ xb,
                                               const float* __restrict__ wq, bf16_t* __restrict__ wqb,
                                               const float* __restrict__ wo, bf16_t* __restrict__ wob,
                                               float* __restrict__ cosT, float* __restrict__ sinT) {
  int i = blockIdx.x * 256 + threadIdx.x;
  if (i < 5767168) {                     // float4 conversions
    const float* in; bf16_t* out; int idx;
    if (i < 2097152)      { in = x;  out = xb;  idx = i; }
    else if (i < 4718592) { in = wq; out = wqb; idx = i - 2097152; }
    else                  { in = wo; out = wob; idx = i - 4718592; }
    float4 v = ((const float4*)in)[idx];
    bf16x4v o;
    o[0] = (__bf16)v.x; o[1] = (__bf16)v.y; o[2] = (__bf16)v.z; o[3] = (__bf16)v.w;
    *(bf16x4v*)(out + (size_t)idx * 4) = o;
  } else {                               // rope tables: 2048*64 entries
    int idx = i - 5767168;
    int s = idx >> 6, fi = idx & 63;
    float inv = __builtin_amdgcn_exp2f(-(float)fi * (19.931568569324174f / 64.0f));
    float f = (float)s * inv;
    cosT[idx] = cosf(f);
    sinT[idx] = sinf(f);
  }
}

// ------- GEMM1: single-buffered <4,NI>, 2 blocks/CU anti-phase overlap (R19) ----
template<int NI, typename OT>
__global__ __launch_bounds__(512, 4) void gemm4s(const bf16_t* __restrict__ A,
                                                 const bf16_t* __restrict__ B,
                                                 OT* __restrict__ C,
                                                 int M, int N, int K) {
  constexpr int BM = 128;
  constexpr int BN = NI * 64;
  constexpr int NA = 2;
  constexpr int NB = NI;
  constexpr int ST = NA + NB;

  __shared__ bf16_t LA[BM * 64];
  __shared__ bf16_t LB[BN * 64];

  int nb = N / BN;
  int cpx = gridDim.x >> 3;              // grid divisible by 8
  int bid = blockIdx.x;
  int swz = (bid & 7) * cpx + (bid >> 3);
  int bm = swz / nb, bn = swz % nb;
  int m0 = bm * BM, n0 = bn * BN;
  int tid = threadIdx.x, lane = tid & 63, wv = tid >> 6;
  int wr = wv >> 2, wc = wv & 3, lr = lane & 15, g = lane >> 4;
  int T = K >> 6;

  auto stageI = [&](int kt, int s) {
    int k0 = kt << 6;
    if (s < NA) {
      int c = s * 512 + tid;
      int row = c >> 3, lc = (c & 7) ^ (row & 7);
      __builtin_amdgcn_global_load_lds(
          (const __attribute__((address_space(1))) void*)(A + (size_t)(m0 + row) * K + k0 + lc * 8),
          (__attribute__((address_space(3))) void*)&LA[(s * 512 + wv * 64) * 8], 16, 0, 0);
    } else {
      int c = (s - NA) * 512 + tid;
      int row = c >> 3, lc = (c & 7) ^ (row & 7);
      __builtin_amdgcn_global_load_lds(
          (const __attribute__((address_space(1))) void*)(B + (size_t)(n0 + row) * K + k0 + lc * 8),
          (__attribute__((address_space(3))) void*)&LB[((s - NA) * 512 + wv * 64) * 8], 16, 0, 0);
    }
  };

  f32x4 acc[4][NI];
#pragma unroll
  for (int i = 0; i < 4; i++)
#pragma unroll
    for (int j = 0; j < NI; j++)
#pragma unroll
      for (int r = 0; r < 4; r++) acc[i][j][r] = 0.f;

  int ofk0 = ((0 + g) ^ (lr & 7)) << 3;
  int ofk1 = ((4 + g) ^ (lr & 7)) << 3;
  int offA = (wr * 64 + lr) * 64;
  int offB = (wc * (NI * 16) + lr) * 64;

  for (int t = 0; t < T; t++) {
#pragma unroll
    for (int s = 0; s < ST; s++) stageI(t, s);
    asm volatile("s_waitcnt vmcnt(0)" ::: "memory");
    __builtin_amdgcn_s_barrier();
    asm volatile("" ::: "memory");

#pragma unroll
    for (int ks = 0; ks < 2; ks++) {
      const int ofk = ks ? ofk1 : ofk0;
      bf16x8 bq[NI];
#pragma unroll
      for (int ni = 0; ni < NI; ni++) bq[ni] = *(const bf16x8*)&LB[offB + ni * 1024 + ofk];
#pragma unroll
      for (int i = 0; i < 4; i++) {
        bf16x8 af = *(const bf16x8*)&LA[offA + i * 1024 + ofk];
#pragma unroll
        for (int ni = 0; ni < NI; ni++)
          acc[i][ni] = __builtin_amdgcn_mfma_f32_16x16x32_bf16(af, bq[ni], acc[i][ni], 0, 0, 0);
      }
    }

    if (t + 1 < T) {
      asm volatile("s_waitcnt lgkmcnt(0)" ::: "memory");
      __builtin_amdgcn_s_barrier();
      asm volatile("" ::: "memory");
    }
  }

#pragma unroll
  for (int mi = 0; mi < 4; mi++)
#pragma unroll
    for (int ni = 0; ni < NI; ni++) {
      int m = m0 + wr * 64 + mi * 16 + g * 4;
      int n = n0 + wc * (NI * 16) + ni * 16 + lr;
#pragma unroll
      for (int r = 0; r < 4; r++) C[(size_t)(m + r) * N + n] = (OT)acc[mi][ni][r];
    }
}

// ---------------- bf16 NT GEMM: free-flow compute, ONE barrier per K-tile -------
// (R13/R14-proven structure; used for GEMM2.)
template<int MI, int NI, typename OT>
__global__ __launch_bounds__(512) void gemm8p(const bf16_t* __restrict__ A,
                                              const bf16_t* __restrict__ B,
                                              OT* __restrict__ C,
                                              int M, int N, int K) {
  constexpr int BM = MI * 32;
  constexpr int BN = NI * 64;
  constexpr int NA = BM / 64;
  constexpr int NB = BN / 64;
  constexpr int ST = NA + NB;

  __shared__ bf16_t LA[2][BM * 64];
  __shared__ bf16_t LB[2][BN * 64];

  int nb = N / BN;
  int cpx = gridDim.x >> 3;
  int bid = blockIdx.x;
  int swz = (bid & 7) * cpx + (bid >> 3);
  int bm = swz / nb, bn = swz % nb;
  int m0 = bm * BM, n0 = bn * BN;
  int tid = threadIdx.x, lane = tid & 63, wv = tid >> 6;
  int wr = wv >> 2, wc = wv & 3, lr = lane & 15, g = lane >> 4;
  int T = K >> 6;

  auto stageI = [&](int kt, int bi, int s) {
    int k0 = kt << 6;
    if (s < NA) {
      int c = s * 512 + tid;
      int row = c >> 3, lc = (c & 7) ^ (row & 7);
      __builtin_amdgcn_global_load_lds(
          (const __attribute__((address_space(1))) void*)(A + (size_t)(m0 + row) * K + k0 + lc * 8),
          (__attribute__((address_space(3))) void*)&LA[bi][(s * 512 + wv * 64) * 8], 16, 0, 0);
    } else {
      int c = (s - NA) * 512 + tid;
      int row = c >> 3, lc = (c & 7) ^ (row & 7);
      __builtin_amdgcn_global_load_lds(
          (const __attribute__((address_space(1))) void*)(B + (size_t)(n0 + row) * K + k0 + lc * 8),
          (__attribute__((address_space(3))) void*)&LB[bi][((s - NA) * 512 + wv * 64) * 8], 16, 0, 0);
    }
  };

  f32x4 acc[MI][NI];
#pragma unroll
  for (int i = 0; i < MI; i++)
#pragma unroll
    for (int j = 0; j < NI; j++)
#pragma unroll
      for (int r = 0; r < 4; r++) acc[i][j][r] = 0.f;

#pragma unroll
  for (int s = 0; s < ST; s++) stageI(0, 0, s);
  asm volatile("s_waitcnt vmcnt(0)" ::: "memory");
  __builtin_amdgcn_s_barrier();
  asm volatile("" ::: "memory");

  int ofk0 = ((0 + g) ^ (lr & 7)) << 3;
  int ofk1 = ((4 + g) ^ (lr & 7)) << 3;
  int offA = (wr * (MI * 16) + lr) * 64;
  int offB = (wc * (NI * 16) + lr) * 64;

  for (int t = 0; t < T; t++) {
    int bi = t & 1, bo = bi ^ 1;
    const bf16_t* la = LA[bi];
    const bf16_t* lb = LB[bi];
    bool pre = (t + 1 < T);
    if (pre) {
#pragma unroll
      for (int s = 0; s < ST; s++) stageI(t + 1, bo, s);
    }

    bf16x8 bq0[NI], bq1[NI];
#pragma unroll
    for (int ni = 0; ni < NI; ni++) bq0[ni] = *(const bf16x8*)&lb[offB + ni * 1024 + ofk0];
#pragma unroll
    for (int ni = 0; ni < NI; ni++) bq1[ni] = *(const bf16x8*)&lb[offB + ni * 1024 + ofk1];
#pragma unroll
    for (int q = 0; q < MI / 4; q++) {
      bf16x8 af0[4], af1[4];
#pragma unroll
      for (int i = 0; i < 4; i++)
        af0[i] = *(const bf16x8*)&la[offA + (q * 4 + i) * 1024 + ofk0];
#pragma unroll
      for (int i = 0; i < 4; i++)
#pragma unroll
        for (int ni = 0; ni < NI; ni++)
          acc[q * 4 + i][ni] =
              __builtin_amdgcn_mfma_f32_16x16x32_bf16(af0[i], bq0[ni], acc[q * 4 + i][ni], 0, 0, 0);
#pragma unroll
      for (int i = 0; i < 4; i++)
        af1[i] = *(const bf16x8*)&la[offA + (q * 4 + i) * 1024 + ofk1];
#pragma unroll
      for (int i = 0; i < 4; i++)
#pragma unroll
        for (int ni = 0; ni < NI; ni++)
          acc[q * 4 + i][ni] =
              __builtin_amdgcn_mfma_f32_16x16x32_bf16(af1[i], bq1[ni], acc[q * 4 + i][ni], 0, 0, 0);
    }

    if (pre) {
      asm volatile("s_waitcnt vmcnt(0) lgkmcnt(0)" ::: "memory");
      __builtin_amdgcn_s_barrier();
      asm volatile("" ::: "memory");
    }
  }

#pragma unroll
  for (int mi = 0; mi < MI; mi++)
#pragma unroll
    for (int ni = 0; ni < NI; ni++) {
      int m = m0 + wr * (MI * 16) + mi * 16 + g * 4;
      int n = n0 + wc * (NI * 16) + ni * 16 + lr;
#pragma unroll
      for (int r = 0; r < 4; r++) C[(size_t)(m + r) * N + n] = (OT)acc[mi][ni][r];
    }
}

// ---------------- fused per-head LayerNorm + RoPE -> bf16 Q(B,H,S,D), K(B,KV,S,D) ----
__global__ __launch_bounds__(256) void ln_rope(const bf16_t* __restrict__ qkv,
                                               const float* __restrict__ qw, const float* __restrict__ qb,
                                               const float* __restrict__ kw, const float* __restrict__ kb,
                                               const float* __restrict__ cosT, const float* __restrict__ sinT,
                                               bf16_t* __restrict__ Qr, bf16_t* __restrict__ Kr) {
  int row = blockIdx.x;              // b*2048 + s
  int b = row >> 11, s = row & 2047;
  int tid = threadIdx.x, gi = tid >> 4, li = tid & 15;
  const bf16_t* base = qkv + (size_t)row * 5120;
  float4 c4 = *(const float4*)(cosT + (s << 6) + (li << 2));
  float4 s4 = *(const float4*)(sinT + (s << 6) + (li << 2));
#pragma unroll
  for (int it = 0; it < 2; it++) {
    int head;
    if (it == 0) head = gi;            // 16 q heads across 16 groups
    else { if (gi >= 4) break; head = 16 + gi; }   // 4 k heads on wave 0
    bool isq = (it == 0);
    int off = isq ? (head << 7) : (4096 + ((head - 16) << 7));
    bf16x8 xv = *(const bf16x8*)(base + off + (li << 3));
    float xf[8];
#pragma unroll
    for (int j = 0; j < 8; j++) xf[j] = (float)xv[j];
    float sum = 0.f;
#pragma unroll
    for (int j = 0; j < 8; j++) sum += xf[j];
#pragma unroll
    for (int m = 1; m < 16; m <<= 1) sum += __shfl_xor(sum, m);
    float mu = sum * 0.0078125f;
    float vs = 0.f;
#pragma unroll
    for (int j = 0; j < 8; j++) { xf[j] -= mu; vs += xf[j] * xf[j]; }
#pragma unroll
    for (int m = 1; m < 16; m <<= 1) vs += __shfl_xor(vs, m);
    float rs = rsqrtf(vs * 0.0078125f + 1e-6f);
    const float* w = isq ? qw : kw;
    const float* bb = isq ? qb : kb;
    float4 w0 = *(const float4*)(w + (li << 3));
    float4 w1 = *(const float4*)(w + (li << 3) + 4);
    float4 b0 = *(const float4*)(bb + (li << 3));
    float4 b1 = *(const float4*)(bb + (li << 3) + 4);
    float y[8];
    y[0] = xf[0] * rs * w0.x + b0.x; y[1] = xf[1] * rs * w0.y + b0.y;
    y[2] = xf[2] * rs * w0.z + b0.z; y[3] = xf[3] * rs * w0.w + b0.w;
    y[4] = xf[4] * rs * w1.x + b1.x; y[5] = xf[5] * rs * w1.y + b1.y;
    y[6] = xf[6] * rs * w1.z + b1.z; y[7] = xf[7] * rs * w1.w + b1.w;
    float cc[4] = { c4.x, c4.y, c4.z, c4.w };
    float ss[4] = { s4.x, s4.y, s4.z, s4.w };
    bf16x8 ov;
#pragma unroll
    for (int p = 0; p < 4; p++) {
      float o0 = y[2 * p] * cc[p] - y[2 * p + 1] * ss[p];
      float o1 = y[2 * p] * ss[p] + y[2 * p + 1] * cc[p];
      if (isq) { o0 *= QSCALE; o1 *= QSCALE; }
      ov[2 * p] = (__bf16)o0; ov[2 * p + 1] = (__bf16)o1;
    }
    size_t dst = isq ? ((((size_t)(b * 16 + head)) * 2048 + s) * 128 + (li << 3))
                     : ((((size_t)(b * 4 + (head - 16))) * 2048 + s) * 128 + (li << 3));
    *(bf16x8*)((isq ? Qr : Kr) + dst) = ov;
  }
}

// ---------------- V transpose: qkv v-slice (B,S,KV,D) -> Vt (B,KV,D,S) bf16 -------
__global__ __launch_bounds__(256) void vtrans(const bf16_t* __restrict__ qkv,
                                              bf16_t* __restrict__ Vt) {
  int bid = blockIdx.x;              // ((b*4+kv)*64 + sb)
  int sb = bid & 63, kv = (bid >> 6) & 3, b = bid >> 8;
  int s0 = sb << 5;
  __shared__ bf16_t T[128 * 33];
  int tid = threadIdx.x;
#pragma unroll
  for (int i = 0; i < 16; i++) {
    int idx = i * 256 + tid;         // 0..4095
    int r = idx >> 7, d = idx & 127;
    T[d * 33 + r] = qkv[((size_t)(b * 2048 + s0 + r)) * 5120 + 4608 + (kv << 7) + d];
  }
  __syncthreads();
#pragma unroll
  for (int j = 0; j < 16; j++) {
    int idx = j * 256 + tid;
    int d = idx >> 5, sc = idx & 31;
    Vt[(((size_t)(b * 4 + kv)) * 128 + d) * 2048 + s0 + sc] = T[d * 33 + sc];
  }
}

// ---------------- causal GQA flash attention + sigmoid gate -> ag bf16 (B,S,H*D) ----
// R21: block = (qb, h, b) with ONE 64-row q-block each (no pr pairing) ->
// 1024 blocks, longest-qb-first LPT. With VGPR 72 + 32KB LDS, ~4-5 blocks/CU
// co-reside -> cross-block latency hiding (R10/R19 mechanism). Inner tile loop
// byte-identical to the verified R14/R19 kernel.
__global__ __launch_bounds__(256, 3) void attn(const bf16_t* __restrict__ Qr,
                                               const bf16_t* __restrict__ Kr,
                                               const bf16_t* __restrict__ Vt,
                                               const bf16_t* __restrict__ qkv,
                                               bf16_t* __restrict__ ag) {
  __shared__ bf16_t Ks[2][32 * 128];   // 16 KB: K tiles, XOR s2(row)
  __shared__ bf16_t Vs[2][128 * 32];   // 16 KB: V^T tiles, XOR (d>>1)&3
  int bid = blockIdx.x;                // 1024 = 32 qb (longest first) * (16 h * 2 b)
  int hb = bid & 31;
  int h = hb & 15, b = hb >> 4;
  int qb = 31 - (bid >> 5);            // 64-row q-block, longest first
  int kvh = h >> 2;
  int tid = threadIdx.x, lane = tid & 63, wv = tid >> 6;
  int lr = lane & 15, g = lane >> 4;
  int r0base = ((lr >> 2) << 3) + (lr & 3);   // pi(lr): A-row -> K-row map

  const bf16_t* Kg = Kr + ((size_t)(b * 4 + kvh)) * 2048 * 128;
  const bf16_t* Vg = Vt + ((size_t)(b * 4 + kvh)) * 128 * 2048;

  auto s2 = [](int row) { return (row & 3) | (((row >> 3) & 1) << 2); };

  auto stage = [&](int buf, int kv0) {
#pragma unroll
    for (int i = 0; i < 2; i++) {      // K: 8 KB, 512 chunks of 16 B
      int c = i * 256 + tid;
      int row = c >> 4, lc = (c & 15) ^ ((row & 3) | (((row >> 3) & 1) << 2));
      __builtin_amdgcn_global_load_lds(
          (const __attribute__((address_space(1))) void*)(Kg + (size_t)(kv0 + row) * 128 + lc * 8),
          (__attribute__((address_space(3))) void*)&Ks[buf][c * 8], 16, 0, 0);
    }
#pragma unroll
    for (int i = 0; i < 2; i++) {      // V: 8 KB
      int c = i * 256 + tid;
      int d = c >> 2, cv = (c & 3) ^ ((d >> 1) & 3);
      __builtin_amdgcn_global_load_lds(
          (const __attribute__((address_space(1))) void*)(Vg + (size_t)d * 2048 + kv0 + cv * 8),
          (__attribute__((address_space(3))) void*)&Vs[buf][c * 8], 16, 0, 0);
    }
  };

  auto sm = [&](const f32x4& s0, const f32x4& s1, int qrow, int kvabs, bool dia,
                float& mrun, float& lsp, bf16x8& pb, f32x4 (&oac)[8]) {
    float tt[8];
#pragma unroll
    for (int r = 0; r < 4; r++) { tt[r] = s0[r]; tt[4 + r] = s1[r]; }
    if (dia) {
#pragma unroll
      for (int r = 0; r < 4; r++) {
        if (kvabs + r > qrow)     tt[r]     = -1e30f;
        if (kvabs + 4 + r > qrow) tt[4 + r] = -1e30f;
      }
    }
    float lm = fmaxf(fmaxf(fmaxf(tt[0], tt[1]), tt[2]),
                     fmaxf(fmaxf(tt[3], tt[4]), fmaxf(fmaxf(tt[5], tt[6]), tt[7])));
    if (__all(lm <= mrun + 8.f)) {      // defer-max common path: lane-local only
      float ps = 0.f;
#pragma unroll
      for (int i = 0; i < 8; i++) {
        float pv = __builtin_amdgcn_exp2f(tt[i] - mrun);
        pb[i] = (__bf16)pv; ps += pv;
      }
      lsp += ps;
    } else {                            // rare rescale path
      float pm = lm;
      pm = fmaxf(pm, __shfl_xor(pm, 16));
      pm = fmaxf(pm, __shfl_xor(pm, 32));
      float mnew = fmaxf(mrun, pm);
      float corr = __builtin_amdgcn_exp2f(mrun - mnew);
      float ps = 0.f;
#pragma unroll
      for (int i = 0; i < 8; i++) {
        float pv = __builtin_amdgcn_exp2f(tt[i] - mnew);
        pb[i] = (__bf16)pv; ps += pv;
      }
      lsp = lsp * corr + ps;
      mrun = mnew;
#pragma unroll
      for (int dt = 0; dt < 8; dt++)
#pragma unroll
        for (int r = 0; r < 4; r++) oac[dt][r] *= corr;
    }
  };

  int qw = (qb << 6) + (wv << 4);      // wave q base (16 rows)
  int qrow = qw + lr;
  int qmax = qw + 15;
  int nt = (qb + 1) << 1;              // 32-wide kv tiles

  const bf16_t* Qg = Qr + (((size_t)(b * 16 + h)) * 2048 + qrow) * 128;
  bf16x8 qf[4];
#pragma unroll
  for (int ds = 0; ds < 4; ds++) qf[ds] = *(const bf16x8*)(Qg + ds * 32 + g * 8);

  f32x4 oa[8];
#pragma unroll
  for (int i = 0; i < 8; i++)
#pragma unroll
    for (int r = 0; r < 4; r++) oa[i][r] = 0.f;
  float mrun = -1e30f, lsp = 0.f;

  stage(0, 0);
  asm volatile("s_waitcnt vmcnt(0)" ::: "memory");
  __builtin_amdgcn_s_barrier();
  asm volatile("" ::: "memory");
  for (int t = 0; t < nt; t++) {
    int cur = t & 1;
    if (t + 1 < nt) stage(cur ^ 1, (t + 1) << 5);
    int kvb = t << 5;
    if (kvb <= qmax) {
      const bf16_t* kb = Ks[cur];
      const bf16_t* vb = Vs[cur];
      int ra = r0base, rb2 = r0base + 4;
      int sa = s2(ra), sb2 = s2(rb2);
      bf16x8 a0[4], a1[4];
#pragma unroll
      for (int ds = 0; ds < 4; ds++) {
        a0[ds] = *(const bf16x8*)&kb[ra * 128 + (((ds * 4 + g) ^ sa) << 3)];
        a1[ds] = *(const bf16x8*)&kb[rb2 * 128 + (((ds * 4 + g) ^ sb2) << 3)];
      }
      f32x4 s0, s1;
#pragma unroll
      for (int r = 0; r < 4; r++) { s0[r] = 0.f; s1[r] = 0.f; }
      __builtin_amdgcn_s_setprio(1);
#pragma unroll
      for (int ds = 0; ds < 4; ds++) {
        s0 = __builtin_amdgcn_mfma_f32_16x16x32_bf16(a0[ds], qf[ds], s0, 0, 0, 0);
        s1 = __builtin_amdgcn_mfma_f32_16x16x32_bf16(a1[ds], qf[ds], s1, 0, 0, 0);
      }
      __builtin_amdgcn_s_setprio(0);
      int kvabs = kvb + (g << 3);
      bool dia = (kvb + 31 > qw);
      bf16x8 pb;
      sm(s0, s1, qrow, kvabs, dia, mrun, lsp, pb, oa);
      __builtin_amdgcn_s_setprio(1);
#pragma unroll
      for (int dt = 0; dt < 8; dt++) {
        int d = dt * 16 + lr;
        bf16x8 va = *(const bf16x8*)&vb[d * 32 + ((g ^ ((d >> 1) & 3)) << 3)];
        oa[dt] = __builtin_amdgcn_mfma_f32_16x16x32_bf16(va, pb, oa[dt], 0, 0, 0);
      }
      __builtin_amdgcn_s_setprio(0);
    }
    asm volatile("s_waitcnt vmcnt(0) lgkmcnt(0)" ::: "memory");
    __builtin_amdgcn_s_barrier();
    asm volatile("" ::: "memory");
  }

  float ls = lsp + __shfl_xor(lsp, 16);
  ls += __shfl_xor(ls, 32);
  float invl = __builtin_amdgcn_rcpf(ls);

  size_t ob = ((size_t)b * 2048 + qrow) * 2048 + (h << 7);
  size_t gb = ((size_t)b * 2048 + qrow) * 5120 + 2048 + (h << 7);
#pragma unroll
  for (int dt = 0; dt < 8; dt++) {
    int d = dt * 16 + (g << 2);
    bf16x4v gt = *(const bf16x4v*)(qkv + gb + d);
    bf16x4v o;
#pragma unroll
    for (int r = 0; r < 4; r++)
      o[r] = (__bf16)(oa[dt][r] * invl *
                      __builtin_amdgcn_rcpf(1.f + __builtin_amdgcn_exp2f(-(float)gt[r] * LOG2E)));
    *(bf16x4v*)(ag + ob + d) = o;
  }
}

// ---------------- launch ----------------
extern "C" void kernel_launch(void* const* d_in, const int* in_sizes, int n_in,
                              void* d_out, int out_size, void* d_ws, size_t ws_size,
                              hipStream_t stream) {
  const float* x    = (const float*)d_in[0];
  const float* wqkv = (const float*)d_in[1];
  const float* wo   = (const float*)d_in[2];
  const float* qnw  = (const float*)d_in[3];
  const float* qnb  = (const float*)d_in[4];
  const float* knw  = (const float*)d_in[5];
  const float* knb  = (const float*)d_in[6];
  float* out = (float*)d_out;

  char* p = (char*)d_ws;
  bf16_t* xb  = (bf16_t*)p;           // 16 MB, reused as ag after GEMM1
  bf16_t* ag  = xb;
  p += (size_t)16777216;
  bf16_t* wqb = (bf16_t*)p;           // 20 MB, reused as Qr after GEMM1
  bf16_t* Qr  = wqb;
  p += (size_t)20971520;
  bf16_t* wob = (bf16_t*)p; p += (size_t)8388608;
  bf16_t* qkv = (bf16_t*)p; p += (size_t)41943040;   // bf16 qkv (B,S,5120)
  bf16_t* Kr  = (bf16_t*)p; p += (size_t)4194304;
  bf16_t* Vt  = (bf16_t*)p; p += (size_t)4194304;
  float* cosT = (float*)p;  p += (size_t)524288;
  float* sinT = (float*)p;  p += (size_t)524288;

  cvt_all<<<23040, 256, 0, stream>>>(x, xb, wqkv, wqb, wo, wob, cosT, sinT);

  // qkv = x @ w_qkv^T   (4096 x 5120 x K=2048): 512 blocks, single-buffer, 2/CU
  gemm4s<5, bf16_t><<<512, 512, 0, stream>>>(xb, wqb, qkv, 4096, 5120, 2048);

  ln_rope<<<4096, 256, 0, stream>>>(qkv, qnw, qnb, knw, knb, cosT, sinT, Qr, Kr);
  vtrans<<<512, 256, 0, stream>>>(qkv, Vt);

  attn<<<1024, 256, 0, stream>>>(Qr, Kr, Vt, qkv, ag);

  // out = ag @ w_o^T    (4096 x 2048 x K=2048): BM=128, BN=256 -> 256 blocks, f32 out
  gemm8p<4, 4, float><<<256, 512, 0, stream>>>(ag, wob, out, 4096, 2048, 2048);
}